// Round 1
// baseline (1651.034 us; speedup 1.0000x reference)
//
#include <hip/hip_runtime.h>

#define S 2048
#define HID 5120
#define NH 40
#define HD 128

typedef unsigned short u16;
typedef __attribute__((ext_vector_type(8))) short short8;
typedef __attribute__((ext_vector_type(4))) float f32x4;

__device__ __forceinline__ u16 f2bf(float f) {
  union { float f; unsigned u; } x; x.f = f;
  unsigned r = x.u + 0x7fffu + ((x.u >> 16) & 1u);
  return (u16)(r >> 16);
}

// async global->LDS, 16B per lane; LDS dest = wave-uniform base + lane*16
__device__ __forceinline__ void gl_lds16(const void* g, void* l) {
  __builtin_amdgcn_global_load_lds((__attribute__((address_space(1))) void*)g,
                                   (__attribute__((address_space(3))) void*)l,
                                   16, 0, 0);
}

// ---------------- fp32 -> bf16 convert ----------------
__global__ __launch_bounds__(256) void cvt4(const float4* __restrict__ s,
                                            ushort4* __restrict__ d, int n4) {
  int i = blockIdx.x * 256 + threadIdx.x;
  if (i >= n4) return;
  float4 v = s[i];
  ushort4 o;
  o.x = f2bf(v.x); o.y = f2bf(v.y); o.z = f2bf(v.z); o.w = f2bf(v.w);
  d[i] = o;
}

// ---------------- bf16 GEMM: C[M,N] = A[M,K] * B[N,K]^T ----------------
// 128x128 tile, BK=64, 4 waves (2x2 of 64x64), 16x16x32 MFMA.
// LDS XOR-swizzle: LDS[row][cb] holds G[row][cb ^ (row&7)] (cb = 16B col-block)
// mode 0: fp32 C out.  mode 1: qkv scatter (q scaled, v transposed).
__global__ __launch_bounds__(256) void gemm_bt(
    const u16* __restrict__ A, const u16* __restrict__ B,
    int N, int K,
    float* __restrict__ C,
    u16* __restrict__ qb, u16* __restrict__ kb, u16* __restrict__ vtb,
    int mode)
{
  __shared__ __align__(16) u16 As[128 * 64];
  __shared__ __align__(16) u16 Bs[128 * 64];
  const int tid = threadIdx.x;
  const int lane = tid & 63;
  const int wid = tid >> 6;
  const int wm = wid >> 1, wn = wid & 1;
  const int l16 = lane & 15, quad = lane >> 4;
  const int m0 = blockIdx.x * 128, n0 = blockIdx.y * 128;

  f32x4 acc[4][4];
#pragma unroll
  for (int i = 0; i < 4; ++i)
#pragma unroll
    for (int j = 0; j < 4; ++j)
      acc[i][j] = (f32x4){0.f, 0.f, 0.f, 0.f};

  const int srow = lane >> 3;   // 0..7 within 8-row chunk
  const int scb = lane & 7;     // LDS col-block this lane fills

  for (int k0 = 0; k0 < K; k0 += 64) {
#pragma unroll
    for (int cc = 0; cc < 4; ++cc) {
      int c = wid * 4 + cc;
      int row = c * 8 + srow;
      int cb = scb ^ (row & 7);
      gl_lds16(A + (long)(m0 + row) * K + k0 + cb * 8, &As[c * 512]);
    }
#pragma unroll
    for (int cc = 0; cc < 4; ++cc) {
      int c = wid * 4 + cc;
      int row = c * 8 + srow;
      int cb = scb ^ (row & 7);
      gl_lds16(B + (long)(n0 + row) * K + k0 + cb * 8, &Bs[c * 512]);
    }
    __syncthreads();   // drains vmcnt (global_load_lds) + barrier
#pragma unroll
    for (int kk = 0; kk < 64; kk += 32) {
      short8 af[4], bg[4];
      const int cb0 = (kk >> 3) + quad;
#pragma unroll
      for (int i = 0; i < 4; ++i) {
        int row = wm * 64 + i * 16 + l16;
        af[i] = *(const short8*)&As[row * 64 + (cb0 ^ (row & 7)) * 8];
      }
#pragma unroll
      for (int j = 0; j < 4; ++j) {
        int row = wn * 64 + j * 16 + l16;
        bg[j] = *(const short8*)&Bs[row * 64 + (cb0 ^ (row & 7)) * 8];
      }
#pragma unroll
      for (int i = 0; i < 4; ++i)
#pragma unroll
        for (int j = 0; j < 4; ++j)
          acc[i][j] = __builtin_amdgcn_mfma_f32_16x16x32_bf16(af[i], bg[j], acc[i][j], 0, 0, 0);
    }
    __syncthreads();
  }

  if (mode == 0) {
#pragma unroll
    for (int i = 0; i < 4; ++i)
#pragma unroll
      for (int r = 0; r < 4; ++r) {
        int row = m0 + wm * 64 + i * 16 + quad * 4 + r;
#pragma unroll
        for (int j = 0; j < 4; ++j) {
          int col = n0 + wn * 64 + j * 16 + l16;
          C[(long)row * N + col] = acc[i][j][r];
        }
      }
  } else {
    // n-tile is 128 wide == HD, so (which, head) are block-uniform
    const int which = n0 / HID;
    const int head = (n0 % HID) >> 7;
    const float qs = 0.08838834764831845f;  // 1/sqrt(128), folded into q
#pragma unroll
    for (int i = 0; i < 4; ++i)
#pragma unroll
      for (int j = 0; j < 4; ++j)
#pragma unroll
        for (int r = 0; r < 4; ++r) {
          int sI = m0 + wm * 64 + i * 16 + quad * 4 + r;  // sequence index
          int d = wn * 64 + j * 16 + l16;
          float v = acc[i][j][r];
          if (which == 0)      qb[((long)head * S + sI) * HD + d] = f2bf(v * qs);
          else if (which == 1) kb[((long)head * S + sI) * HD + d] = f2bf(v);
          else                 vtb[((long)head * HD + d) * S + sI] = f2bf(v);  // V^T
        }
  }
}

// ---------------- flash attention: Q-tile 64, K-tile 64 ----------------
// q,k: [NH][S][HD] bf16 (q pre-scaled), v: [NH][HD][S] bf16 (transposed)
// out: [S][HID] bf16
__global__ __launch_bounds__(256) void attn_kernel(
    const u16* __restrict__ qg, const u16* __restrict__ kg,
    const u16* __restrict__ vg, u16* __restrict__ og)
{
  __shared__ __align__(16) u16 Qs[64 * 128];   // [q][d]
  __shared__ __align__(16) u16 Ks[64 * 128];   // [k][d]; aliased by Ps[64][64]
  __shared__ __align__(16) u16 Vs[128 * 64];   // [d][k]  (V^T tile)
  __shared__ float redm[2][64];
  __shared__ float reds[2][64];

  const int tid = threadIdx.x;
  const int lane = tid & 63;
  const int wid = tid >> 6;
  const int wm = wid >> 1, wn = wid & 1;
  const int l16 = lane & 15, quad = lane >> 4;
  const int qt = blockIdx.x;
  const int h = blockIdx.y;
  const int q0 = qt * 64;

  u16* Ps = Ks;  // P overwrites K tile after S-compute (barrier-protected)

  {
    const u16* src = qg + ((long)h * S + q0) * HD;
#pragma unroll
    for (int cc = 0; cc < 4; ++cc) {
      int c = wid * 4 + cc;
      int row = c * 4 + (lane >> 4);
      int cb = (lane & 15) ^ (row & 7);
      gl_lds16(src + row * HD + cb * 8, &Qs[c * 512]);
    }
  }

  f32x4 acc_o[2][4];
#pragma unroll
  for (int i = 0; i < 2; ++i)
#pragma unroll
    for (int j = 0; j < 4; ++j)
      acc_o[i][j] = (f32x4){0.f, 0.f, 0.f, 0.f};
  float m_st[2][4], l_st[2][4];
#pragma unroll
  for (int i = 0; i < 2; ++i)
#pragma unroll
    for (int r = 0; r < 4; ++r) { m_st[i][r] = -1e30f; l_st[i][r] = 0.f; }

  for (int kt = 0; kt <= qt; ++kt) {
    __syncthreads();  // prev iter's Ps/Vs reads done (also covers Q stage on iter 0)
    {
      const u16* ksrc = kg + ((long)h * S + kt * 64) * HD;
#pragma unroll
      for (int cc = 0; cc < 4; ++cc) {
        int c = wid * 4 + cc;
        int row = c * 4 + (lane >> 4);
        int cb = (lane & 15) ^ (row & 7);
        gl_lds16(ksrc + row * HD + cb * 8, &Ks[c * 512]);
      }
      const u16* vsrc = vg + (long)h * HD * S + kt * 64;
#pragma unroll
      for (int cc = 0; cc < 4; ++cc) {
        int c = wid * 4 + cc;
        int row = c * 8 + (lane >> 3);
        int cb = (lane & 7) ^ (row & 7);
        gl_lds16(vsrc + (long)row * S + cb * 8, &Vs[c * 512]);
      }
    }
    __syncthreads();

    // ---- S = Q K^T (64x64, each wave 32x32) ----
    f32x4 acc_s[2][2];
#pragma unroll
    for (int i = 0; i < 2; ++i)
#pragma unroll
      for (int j = 0; j < 2; ++j)
        acc_s[i][j] = (f32x4){0.f, 0.f, 0.f, 0.f};
#pragma unroll
    for (int kk = 0; kk < 128; kk += 32) {
      short8 aq[2], bk[2];
      const int cb0 = (kk >> 3) + quad;
#pragma unroll
      for (int i = 0; i < 2; ++i) {
        int row = wm * 32 + i * 16 + l16;
        aq[i] = *(const short8*)&Qs[row * 128 + (cb0 ^ (row & 7)) * 8];
      }
#pragma unroll
      for (int j = 0; j < 2; ++j) {
        int row = wn * 32 + j * 16 + l16;
        bk[j] = *(const short8*)&Ks[row * 128 + (cb0 ^ (row & 7)) * 8];
      }
#pragma unroll
      for (int i = 0; i < 2; ++i)
#pragma unroll
        for (int j = 0; j < 2; ++j)
          acc_s[i][j] = __builtin_amdgcn_mfma_f32_16x16x32_bf16(aq[i], bk[j], acc_s[i][j], 0, 0, 0);
    }

    // ---- causal mask (only diagonal tile) ----
    if (kt == qt) {
#pragma unroll
      for (int i = 0; i < 2; ++i)
#pragma unroll
        for (int j = 0; j < 2; ++j)
#pragma unroll
          for (int r = 0; r < 4; ++r) {
            int row = wm * 32 + i * 16 + quad * 4 + r;
            int col = wn * 32 + j * 16 + l16;
            if (col > row) acc_s[i][j][r] = -1e30f;
          }
    }

    // ---- row max: per-wave shfl over 16 cols, cross-wave via LDS ----
#pragma unroll
    for (int i = 0; i < 2; ++i)
#pragma unroll
      for (int r = 0; r < 4; ++r) {
        float v = fmaxf(acc_s[i][0][r], acc_s[i][1][r]);
        v = fmaxf(v, __shfl_xor(v, 1));
        v = fmaxf(v, __shfl_xor(v, 2));
        v = fmaxf(v, __shfl_xor(v, 4));
        v = fmaxf(v, __shfl_xor(v, 8));
        if (l16 == 0) redm[wn][wm * 32 + i * 16 + quad * 4 + r] = v;
      }
    __syncthreads();  // redm ready; also: all waves done with Ks -> Ps writable

    float alpha[2][4], mnew[2][4], psum[2][4];
#pragma unroll
    for (int i = 0; i < 2; ++i)
#pragma unroll
      for (int r = 0; r < 4; ++r) {
        int row = wm * 32 + i * 16 + quad * 4 + r;
        float mn = fmaxf(m_st[i][r], fmaxf(redm[0][row], redm[1][row]));
        mnew[i][r] = mn;
        alpha[i][r] = __expf(m_st[i][r] - mn);
        m_st[i][r] = mn;
        psum[i][r] = 0.f;
      }
    // P = exp(S - mnew): write bf16 to Ps (C-layout -> LDS -> A-layout)
#pragma unroll
    for (int i = 0; i < 2; ++i)
#pragma unroll
      for (int j = 0; j < 2; ++j)
#pragma unroll
        for (int r = 0; r < 4; ++r) {
          int row = wm * 32 + i * 16 + quad * 4 + r;
          int col = wn * 32 + j * 16 + l16;
          float p = __expf(acc_s[i][j][r] - mnew[i][r]);
          psum[i][r] += p;
          Ps[row * 64 + ((col >> 3) ^ (row & 7)) * 8 + (col & 7)] = f2bf(p);
        }
#pragma unroll
    for (int i = 0; i < 2; ++i)
#pragma unroll
      for (int r = 0; r < 4; ++r) {
        float v = psum[i][r];
        v += __shfl_xor(v, 1);
        v += __shfl_xor(v, 2);
        v += __shfl_xor(v, 4);
        v += __shfl_xor(v, 8);
        if (l16 == 0) reds[wn][wm * 32 + i * 16 + quad * 4 + r] = v;
      }
    __syncthreads();  // Ps + reds ready

    // ---- rescale O, update l ----
#pragma unroll
    for (int i = 0; i < 2; ++i)
#pragma unroll
      for (int r = 0; r < 4; ++r) {
        int row = wm * 32 + i * 16 + quad * 4 + r;
        l_st[i][r] = alpha[i][r] * l_st[i][r] + reds[0][row] + reds[1][row];
#pragma unroll
        for (int j = 0; j < 4; ++j)
          acc_o[i][j][r] *= alpha[i][r];
      }
    // ---- O += P V   (each wave: rows wm*32+32, d-cols wn*64+64) ----
#pragma unroll
    for (int kk = 0; kk < 64; kk += 32) {
      short8 ap[2], bv[4];
      const int cb0 = (kk >> 3) + quad;
#pragma unroll
      for (int i = 0; i < 2; ++i) {
        int m = wm * 32 + i * 16 + l16;
        ap[i] = *(const short8*)&Ps[m * 64 + (cb0 ^ (m & 7)) * 8];
      }
#pragma unroll
      for (int j = 0; j < 4; ++j) {
        int n = wn * 64 + j * 16 + l16;
        bv[j] = *(const short8*)&Vs[n * 64 + (cb0 ^ (n & 7)) * 8];
      }
#pragma unroll
      for (int i = 0; i < 2; ++i)
#pragma unroll
        for (int j = 0; j < 4; ++j)
          acc_o[i][j] = __builtin_amdgcn_mfma_f32_16x16x32_bf16(ap[i], bv[j], acc_o[i][j], 0, 0, 0);
    }
  }

  // ---- epilogue: O / l -> bf16 [S][HID] ----
#pragma unroll
  for (int i = 0; i < 2; ++i)
#pragma unroll
    for (int r = 0; r < 4; ++r) {
      int row = wm * 32 + i * 16 + quad * 4 + r;
      float inv = 1.f / l_st[i][r];
#pragma unroll
      for (int j = 0; j < 4; ++j) {
        int d = wn * 64 + j * 16 + l16;
        og[(long)(q0 + row) * HID + h * HD + d] = f2bf(acc_o[i][j][r] * inv);
      }
    }
}

// ---------------- host ----------------
extern "C" void kernel_launch(void* const* d_in, const int* in_sizes, int n_in,
                              void* d_out, int out_size, void* d_ws, size_t ws_size,
                              hipStream_t stream) {
  const float* hs = (const float*)d_in[0];
  const float* wp = (const float*)d_in[1];
  const float* wo = (const float*)d_in[2];
  float* out = (float*)d_out;
  char* ws = (char*)d_ws;

  // ws layout (bytes)
  u16* hsb = (u16*)(ws);                  //  20,971,520  hs bf16 [2048][5120]
  u16* wpb = (u16*)(ws + 20971520L);      // 157,286,400  W_pack bf16 [15360][5120]
  u16* wob = (u16*)(ws + 178257920L);     //  52,428,800  o_proj bf16 [5120][5120]
  u16* qb  = (u16*)(ws + 230686720L);     //  20,971,520  q bf16 [40][2048][128] (scaled)
  u16* kb  = (u16*)(ws + 251658240L);     //  20,971,520  k bf16 [40][2048][128]
  u16* vtb = (u16*)(ws + 272629760L);     //  20,971,520  v^T bf16 [40][128][2048]
  u16* aob = (u16*)(ws + 293601280L);     //  20,971,520  attn out bf16 [2048][5120]
  if (ws_size < 314572800UL) return;      // need 300 MB

  cvt4<<<10240, 256, 0, stream>>>((const float4*)hs, (ushort4*)hsb, 2621440);
  cvt4<<<76800, 256, 0, stream>>>((const float4*)wp, (ushort4*)wpb, 19660800);
  cvt4<<<25600, 256, 0, stream>>>((const float4*)wo, (ushort4*)wob, 6553600);

  // QKV: [2048,15360] = hs @ W_pack^T, scatter to q/k/v^T
  gemm_bt<<<dim3(16, 120), 256, 0, stream>>>(hsb, wpb, 15360, 5120,
                                             nullptr, qb, kb, vtb, 1);
  attn_kernel<<<dim3(32, 40), 256, 0, stream>>>(qb, kb, vtb, aob);
  // out: [2048,5120] = attn_out @ o_proj^T
  gemm_bt<<<dim3(16, 40), 256, 0, stream>>>(aob, wob, 5120, 5120,
                                            out, nullptr, nullptr, nullptr, 0);
}